// Round 11
// baseline (256.658 us; speedup 1.0000x reference)
//
#include <hip/hip_runtime.h>
#include <hip/hip_bf16.h>
#include <cstddef>
#include <cstdint>

typedef unsigned short u16;
typedef unsigned int   u32;

#define Mtok  16384
#define Ncode 8192
#define Kdim  256
#define NSPL  64                  // splits (128 codes each, B-split = 64 KB LDS)
#define NPER  (Ncode / NSPL)      // 128 codes per split
#define NMT   (Mtok / 128)        // 128 m-tiles
#define TH_MARGIN 2.0f            // err budget: 2*(bf16 ~0.25 + pack ~0.5) = 1.5 < 2.0
#define RCHUNK 256                // full-rescue: codes per chunk
#define RNCH  (Ncode / RCHUNK)    // 32 chunks

typedef __bf16 bf16x8 __attribute__((ext_vector_type(8)));
typedef float  f32x4  __attribute__((ext_vector_type(4)));

#define LDSP(p) ((__attribute__((address_space(3))) void*)(p))
#define GPTR(p) ((const __attribute__((address_space(1))) void*)(p))

__device__ __forceinline__ u16 f2bf(float x) {
    __hip_bfloat16 h = __float2bfloat16(x);
    return *reinterpret_cast<u16*>(&h);
}

// ---------------------------------------------------------------------------
// Kernel 1: transpose z -> z_out (fp32), plus bf16 s = -2*z.
// Also zeroes the rescue counter (stream-ordered before k_merge).
__global__ __launch_bounds__(256) void k_prep(const float* __restrict__ z,
        float* __restrict__ z_out, u16* __restrict__ sh, int* __restrict__ count) {
    __shared__ float tile[32][33];
    const int b  = blockIdx.z;
    const int c0 = blockIdx.y * 32;
    const int p0 = blockIdx.x * 32;
    const int tx = threadIdx.x;   // 0..31
    const int ty = threadIdx.y;   // 0..7
    if (b == 0 && c0 == 0 && p0 == 0 && tx == 0 && ty == 0) count[0] = 0;
    const float* src = z + ((size_t)b * Kdim + c0) * 1024 + p0;
#pragma unroll
    for (int i = 0; i < 32; i += 8)
        tile[ty + i][tx] = src[(size_t)(ty + i) * 1024 + tx];
    __syncthreads();
#pragma unroll
    for (int i = 0; i < 32; i += 8) {
        const float v = tile[tx][ty + i];
        const size_t m = (size_t)b * 1024 + p0 + ty + i;
        const int    c = c0 + tx;
        z_out[m * Kdim + c] = v;
        sh[m * Kdim + c] = f2bf(-2.0f * v);
    }
}

// ---------------------------------------------------------------------------
// Kernel 2: per-code ||w||^2 plus bf16 wh. One wave per code row.
__global__ __launch_bounds__(64) void k_wsplit(const float* __restrict__ w,
        float* __restrict__ wnorm, u16* __restrict__ wh) {
    const int row  = blockIdx.x;
    const int lane = threadIdx.x;
    const float4 v = ((const float4*)(w + (size_t)row * Kdim))[lane];
    float s = v.x * v.x + v.y * v.y + v.z * v.z + v.w * v.w;
#pragma unroll
    for (int off = 32; off > 0; off >>= 1)
        s += __shfl_down(s, off, 64);
    if (lane == 0) wnorm[row] = s;
    ushort4 ph;
    u16* hp = (u16*)&ph;
    hp[0] = f2bf(v.x); hp[1] = f2bf(v.y); hp[2] = f2bf(v.z); hp[3] = f2bf(v.w);
    *(ushort4*)(wh + (size_t)row * Kdim + lane * 4) = ph;
}

// ---------------------------------------------------------------------------
// Kernel 3 (round-13): ZERO-PIPELINE block. NSPL=64 -> B-split (128x256 bf16
// = 64 KB) fully resident in LDS, staged ONCE (16 gload_lds/wave), ONE
// barrier, then a pure ds_read+MFMA+top3 loop: no per-round barriers/vmcnt
// (rounds 2-10 showed the barrier drain + top-3 VALU dominate at 4x the
// 33us MFMA floor; the compiler near-optimally schedules sync-free loops).
// PACKED-KEY top-3: key = (bits(max(d,0)) & ~0x1FFF) | global_code_idx.
// Positive-float compare == unsigned -> sorted-3 insert is 5 min/max ops,
// idx rides free, state = 3 regs/slot. Packing truncation <= 0.5 absorbed
// by TH=2.0 (completeness: uncaptured window code forces k3 < lim -> full).
// LDS swizzle (rows = 512 B = 32 chunks): LDS[row][c] holds global chunk
// c ^ (row&7); stage source pre-swizzled (dest is linear per gload_lds),
// read at chunk (ks*4+q)^(l15&7) -> per-16-lane-phase 2 lanes/chunk = free.
__global__ __launch_bounds__(256, 2) void k_mfma(
        const u16* __restrict__ sh, const u16* __restrict__ wh,
        const float* __restrict__ wnorm,
        float* __restrict__ pk1, float* __restrict__ pk2, float* __restrict__ pk3) {
    __shared__ __align__(16) u16 Bs[NPER * Kdim];   // 64 KB
    const int tid  = threadIdx.x;
    const int w    = tid >> 6;          // wave 0..3
    const int lane = tid & 63;
    const int l15  = lane & 15;
    const int q    = lane >> 4;         // 0..3
    const int y    = blockIdx.x & (NSPL - 1);   // split
    const int x    = blockIdx.x / NSPL;         // m-tile
    const int m0   = x * 128;
    const int n0   = y * NPER;
    const int lrow = lane >> 5;         // 0..1 (2 rows per gload_lds call)
    const int lch  = lane & 31;         // dest chunk within row
    const int rsw  = l15 & 7;           // read-side row swizzle

    // ---- stage whole B-split -> LDS (linear dest; source pre-swizzled) ----
#pragma unroll
    for (int t = 0; t < 16; ++t) {
        const int baser = w * 32 + t * 2;             // w*32 % 8 == 0
        const int sch   = lch ^ ((t * 2 + lrow) & 7); // src chunk for dest (row,lch)
        const size_t gb = (size_t)(n0 + baser + lrow) * Kdim + sch * 8;
        __builtin_amdgcn_global_load_lds(GPTR(wh + gb),
            LDSP(Bs + baser * Kdim), 16, 0, 0);
    }
    // ---- A fragments -> registers (64 VGPR) ----
    bf16x8 ah[8][2];
#pragma unroll
    for (int ks = 0; ks < 8; ++ks)
#pragma unroll
        for (int i = 0; i < 2; ++i) {
            const size_t ra = (size_t)(m0 + w * 32 + i * 16 + l15) * Kdim
                              + ks * 32 + q * 8;
            ah[ks][i] = *(const bf16x8*)(sh + ra);
        }
    // ---- wnorm for this split's columns -> regs (L2-hot) ----
    float wn_r[8];
#pragma unroll
    for (int j = 0; j < 8; ++j) wn_r[j] = wnorm[n0 + j * 16 + l15];

    asm volatile("s_waitcnt vmcnt(0)" ::: "memory");
    __builtin_amdgcn_s_barrier();       // the ONLY barrier

    // ---- compute: 64 ds_read + 128 MFMA, sync-free ----
    f32x4 acc[2][8];
#pragma unroll
    for (int j = 0; j < 8; ++j) {
        const float wv = wn_r[j];
#pragma unroll
        for (int i = 0; i < 2; ++i) {
            acc[i][j][0] = wv; acc[i][j][1] = wv;
            acc[i][j][2] = wv; acc[i][j][3] = wv;
        }
    }
    __builtin_amdgcn_s_setprio(1);
#pragma unroll
    for (int ks = 0; ks < 8; ++ks) {
#pragma unroll
        for (int j = 0; j < 8; ++j) {
            const int ro = (j * 16 + l15) * Kdim + (((ks * 4 + q) ^ rsw) * 8);
            const bf16x8 bh_ = *(const bf16x8*)&Bs[ro];
            acc[0][j] = __builtin_amdgcn_mfma_f32_16x16x32_bf16(ah[ks][0], bh_, acc[0][j], 0, 0, 0);
            acc[1][j] = __builtin_amdgcn_mfma_f32_16x16x32_bf16(ah[ks][1], bh_, acc[1][j], 0, 0, 0);
        }
    }
    __builtin_amdgcn_s_setprio(0);

    // ---- packed-key top-3: slot s=i*4+r -> row m0+w*32+i*16+q*4+r ----
    int jk[8];
#pragma unroll
    for (int j = 0; j < 8; ++j) jk[j] = n0 + j * 16 + l15;   // 13-bit global idx
    const float SENT = __uint_as_float(0x7F7FFFFFu);
    float k1[8], k2[8], k3[8];
#pragma unroll
    for (int s = 0; s < 8; ++s) { k1[s] = SENT; k2[s] = SENT; k3[s] = SENT; }
#pragma unroll
    for (int i = 0; i < 2; ++i)
#pragma unroll
        for (int r = 0; r < 4; ++r) {
            const int s = i * 4 + r;
#pragma unroll
            for (int j = 0; j < 8; ++j) {
                const u32 kb = (__float_as_uint(fmaxf(acc[i][j][r], 0.0f))
                                & 0xFFFFE000u) | (u32)jk[j];
                const float p = __uint_as_float(kb);
                const float nk1 = fminf(k1[s], p);
                const float nk2 = fminf(k2[s], fmaxf(k1[s], p));
                const float nk3 = fminf(k3[s], fmaxf(k2[s], p));
                k1[s] = nk1; k2[s] = nk2; k3[s] = nk3;
            }
        }
    // butterfly merge of sorted triples across the 16 row-lanes
#pragma unroll
    for (int msk = 1; msk < 16; msk <<= 1) {
#pragma unroll
        for (int s = 0; s < 8; ++s) {
            const float b1 = __shfl_xor(k1[s], msk, 64);
            const float b2 = __shfl_xor(k2[s], msk, 64);
            const float b3 = __shfl_xor(k3[s], msk, 64);
            const float w1 = fminf(k1[s], b1);
            const float w2 = fminf(fmaxf(k1[s], b1), fminf(k2[s], b2));
            const float w3 = fminf(fminf(fmaxf(k2[s], b1), fmaxf(k1[s], b2)),
                                   fminf(k3[s], b3));
            k1[s] = w1; k2[s] = w2; k3[s] = w3;
        }
    }
    if (l15 == 0) {
#pragma unroll
        for (int i = 0; i < 2; ++i)
#pragma unroll
            for (int r = 0; r < 4; ++r) {
                const int s = i * 4 + r;
                const int m = m0 + w * 32 + i * 16 + q * 4 + r;
                pk1[(size_t)y * Mtok + m] = k1[s];
                pk2[(size_t)y * Mtok + m] = k2[s];
                pk3[(size_t)y * Mtok + m] = k3[s];
            }
    }
}

// ---------------------------------------------------------------------------
// Kernel 4: merge split top-3 keys -> resolved idx OR candidates OR full.
// Keys are value-packed (idx in low 13 bits) -> pure fmin compares; idx of
// the global winner extracted from gb1. full if any split's 3rd key inside
// the window (possible uncaptured candidate) or candidate overflow.
__global__ __launch_bounds__(256) void k_merge(
        const float* __restrict__ pk1, const float* __restrict__ pk2,
        const float* __restrict__ pk3, int* __restrict__ fidx,
        int* __restrict__ flag, int* __restrict__ cands,
        int* __restrict__ list, int* __restrict__ count) {
    const int t = blockIdx.x * 256 + threadIdx.x;
    float gb1 = __uint_as_float(0x7F7FFFFFu);
#pragma unroll 8
    for (int s = 0; s < NSPL; ++s)
        gb1 = fminf(gb1, pk1[(size_t)s * Mtok + t]);
    const float lim = __uint_as_float(__float_as_uint(gb1) & 0xFFFFE000u)
                      + TH_MARGIN;
    bool full = false;
    int nc = 0;
#pragma unroll 8
    for (int s = 0; s < NSPL; ++s) {
        const float a1 = pk1[(size_t)s * Mtok + t];
        const float a2 = pk2[(size_t)s * Mtok + t];
        const float a3 = pk3[(size_t)s * Mtok + t];
        if (a1 < lim) {
            if (nc < 16) cands[(size_t)t * 16 + nc] = (int)(__float_as_uint(a1) & 0x1FFFu);
            ++nc;
        }
        if (a2 < lim) {
            if (nc < 16) cands[(size_t)t * 16 + nc] = (int)(__float_as_uint(a2) & 0x1FFFu);
            ++nc;
        }
        full = full || (a3 < lim);
    }
    if (nc > 16) full = true;
    fidx[t] = (int)(__float_as_uint(gb1) & 0x1FFFu);
    int f = 0;
    if (full) {
        f = -1;
        const int p = atomicAdd(count, 1);
        list[p] = t;
    } else if (nc >= 2) {
        f = nc;
    }
    flag[t] = f;
}

// ---------------------------------------------------------------------------
// Kernel 5: exact fp32 full rescore (rare safety net), over code chunks.
__global__ __launch_bounds__(256) void k_rescue(
        const float* __restrict__ z_out, const float* __restrict__ w,
        const float* __restrict__ wnorm, const int* __restrict__ list,
        const int* __restrict__ count,
        float* __restrict__ pcv, int* __restrict__ pci) {
    const int bx   = blockIdx.x;       // chunk
    const int tid  = threadIdx.x;
    const int wv   = tid >> 6;
    const int lane = tid & 63;
    __shared__ float rv[4];
    __shared__ int   ri[4];
    const int cnt = count[0];
    for (int it = blockIdx.y; it < cnt; it += gridDim.y) {
        const int t = list[it];
        const float4 zv = *(const float4*)(z_out + (size_t)t * Kdim + lane * 4);
        float bd = 3.0e38f; int bn = 0x7fffffff;
#pragma unroll 4
        for (int i = 0; i < RCHUNK / 4; ++i) {
            const int n = bx * RCHUNK + i * 4 + wv;
            const float4 wr = *(const float4*)(w + (size_t)n * Kdim + lane * 4);
            float s = fmaf(wr.x, zv.x, fmaf(wr.y, zv.y,
                      fmaf(wr.z, zv.z, wr.w * zv.w)));
#pragma unroll
            for (int msk = 1; msk < 64; msk <<= 1)
                s += __shfl_xor(s, msk, 64);
            const float d = wnorm[n] - 2.0f * s;
            if (d < bd) { bd = d; bn = n; }
        }
        if (lane == 0) { rv[wv] = bd; ri[wv] = bn; }
        __syncthreads();
        if (tid == 0) {
            float b = rv[0]; int bi = ri[0];
#pragma unroll
            for (int k = 1; k < 4; ++k)
                if (rv[k] < b || (rv[k] == b && ri[k] < bi)) { b = rv[k]; bi = ri[k]; }
            pcv[(size_t)t * RNCH + bx] = b;
            pci[(size_t)t * RNCH + bx] = bi;
        }
        __syncthreads();
    }
}

// ---------------------------------------------------------------------------
// Kernel 6: gather z_q = weight[idx] + per-token resolution. One wave/token.
// flag==0: fidx. flag==n: exact fp32 rescore of the n candidates (wave
// butterfly dot, all lanes converge). flag==-1: merge RNCH full partials.
__global__ __launch_bounds__(256) void k_gather(
        const float* __restrict__ z_out, const float* __restrict__ w,
        const float* __restrict__ wnorm, const int* __restrict__ fidx,
        const int* __restrict__ flag, const int* __restrict__ cands,
        const float* __restrict__ pcv, const int* __restrict__ pci,
        float* __restrict__ zq, float* __restrict__ idx_out) {
    const int token = blockIdx.x * 4 + (threadIdx.x >> 6);
    const int lane  = threadIdx.x & 63;
    const int f = flag[token];
    int bi = fidx[token];
    if (f == -1) {
        float v = 3.0e38f; int ii = 0x7fffffff;
        if (lane < RNCH) {
            v  = pcv[(size_t)token * RNCH + lane];
            ii = pci[(size_t)token * RNCH + lane];
        }
#pragma unroll
        for (int msk = 1; msk < 64; msk <<= 1) {
            const float ov = __shfl_xor(v, msk, 64);
            const int   oi = __shfl_xor(ii, msk, 64);
            if (ov < v || (ov == v && oi < ii)) { v = ov; ii = oi; }
        }
        bi = ii;
    } else if (f > 0) {
        const float4 zv = *(const float4*)(z_out + (size_t)token * Kdim + lane * 4);
        float bv = 3.0e38f; int bn = 0x7fffffff;
#pragma unroll 1
        for (int c = 0; c < f; ++c) {
            const int n = cands[(size_t)token * 16 + c];
            const float4 wr = *(const float4*)(w + (size_t)n * Kdim + lane * 4);
            float s = fmaf(wr.x, zv.x, fmaf(wr.y, zv.y,
                      fmaf(wr.z, zv.z, wr.w * zv.w)));
#pragma unroll
            for (int msk = 1; msk < 64; msk <<= 1)
                s += __shfl_xor(s, msk, 64);
            const float d = wnorm[n] - 2.0f * s;
            if (d < bv || (d == bv && n < bn)) { bv = d; bn = n; }
        }
        bi = bn;   // uniform: butterfly gives all lanes the full sum
    }
    const float4 u = *(const float4*)(w + (size_t)bi * Kdim + lane * 4);
    *(float4*)(zq + (size_t)token * Kdim + lane * 4) = u;
    if (lane == 0) idx_out[token] = (float)bi;
}

// ---------------------------------------------------------------------------
extern "C" void kernel_launch(void* const* d_in, const int* in_sizes, int n_in,
                              void* d_out, int out_size, void* d_ws, size_t ws_size,
                              hipStream_t stream) {
    const float* z = (const float*)d_in[0];
    const float* w = (const float*)d_in[1];

    float* z_out  = (float*)d_out;                          // [16384, 256]
    float* zq     = z_out + (size_t)Mtok * Kdim;            // [16384, 256]
    float* idxout = zq + (size_t)Mtok * Kdim;               // [16384]

    char* ws = (char*)d_ws;
    u16*   sh    = (u16*)ws;                       ws += (size_t)Mtok * Kdim * 2;
    u16*   wh    = (u16*)ws;                       ws += (size_t)Ncode * Kdim * 2;
    float* wnorm = (float*)ws;                     ws += (size_t)Ncode * 4;
    float* pk1   = (float*)ws;                     ws += (size_t)NSPL * Mtok * 4;
    float* pk2   = (float*)ws;                     ws += (size_t)NSPL * Mtok * 4;
    float* pk3   = (float*)ws;                     ws += (size_t)NSPL * Mtok * 4;
    int*   fidx  = (int*)ws;                       ws += (size_t)Mtok * 4;
    int*   flag  = (int*)ws;                       ws += (size_t)Mtok * 4;
    int*   cands = (int*)ws;                       ws += (size_t)Mtok * 16 * 4;
    int*   list  = (int*)ws;                       ws += (size_t)Mtok * 4;
    int*   count = (int*)ws;                       ws += 256;
    // pcv/pci alias pk1/pk2: pk* are dead after k_merge, and k_rescue
    // (writer) / k_gather (reader) are stream-ordered after it.
    float* pcv   = pk1;                            // [Mtok, RNCH] fits in 4 MB
    int*   pci   = (int*)pk2;

    k_prep<<<dim3(1024 / 32, Kdim / 32, 16), dim3(32, 8), 0, stream>>>(z, z_out, sh, count);
    k_wsplit<<<dim3(Ncode), dim3(64), 0, stream>>>(w, wnorm, wh);
    k_mfma<<<dim3(NSPL * NMT), dim3(256), 0, stream>>>(sh, wh, wnorm,
                                                       pk1, pk2, pk3);
    k_merge<<<dim3(Mtok / 256), dim3(256), 0, stream>>>(pk1, pk2, pk3,
                                                        fidx, flag, cands, list, count);
    k_rescue<<<dim3(RNCH, 64), dim3(256), 0, stream>>>(z_out, w, wnorm, list, count,
                                                       pcv, pci);
    k_gather<<<dim3(Mtok / 4), dim3(256), 0, stream>>>(z_out, w, wnorm, fidx, flag,
                                                       cands, pcv, pci, zq, idxout);
}